// Round 2
// baseline (3052.041 us; speedup 1.0000x reference)
//
#include <hip/hip_runtime.h>
#include <math.h>

// ---------------------------------------------------------------------------
// FRU cell, decomposed:
//   state[f,s](t) = sum_{tau<=t} c_f(tau)*stats[s](tau)   (f>=1; f=0: current only)
//   c_f(t) = (1/L)*cos((2pi/L)*t*f + 2pi*phases[f])
// Scan only carries: Pa[r] = state_acc@Wr  (64 floats) and stats(t-1) (64 floats).
//   recur(t)  = gelu(Pa(t-1) + c0*stats(t-1)@Wr0 + br)
//   stats(t)  = gelu(xstat[b,t] + recur@Wsr + bs)
//   Pa(t)     = Pa(t-1) + stats(t)@M_t,  M_t precomputed (bf16, streamed)
// k_scan v2: ONE WAVE per batch (lane = output index for both stages):
//   - no barriers, no shuffles: full 64-dots per lane, sprev/recur exchanged
//     via LDS broadcast reads (same-address, conflict-free), wave-synchronous.
//   - 4-deep register ring prefetch of MT rows + xstat (covers ~2000+ cyc).
//   - packed f32 FMAs (float2) to halve VALU issue.
// Then: state materialized bf16 (cumsum over t), out = gelu(state@Wo + bo) as
// one big bf16 MFMA GEMM.
// ---------------------------------------------------------------------------

#define TWO_PI 6.283185307179586f
#define INV_L  (1.0f/2048.0f)

typedef unsigned short u16;
typedef __attribute__((ext_vector_type(8))) short bf16x8;   // 8 bf16 = 4 VGPRs
typedef __attribute__((ext_vector_type(4))) float f32x4;
typedef __attribute__((ext_vector_type(2))) float f32x2;

__device__ __forceinline__ float bf2f(u16 u){ return __uint_as_float(((unsigned int)u) << 16); }
__device__ __forceinline__ u16 f2bf(float x){
  unsigned int u = __float_as_uint(x);
  u += 0x7FFFu + ((u >> 16) & 1u);           // round-to-nearest-even
  return (u16)(u >> 16);
}
__device__ __forceinline__ float gelu_tanh(float x){
  // tanh-approx gelu: error <3e-4 abs; attenuated ~50x through the (1/L) cumsum.
  float y = 0.7978845608028654f * x * (1.0f + 0.044715f * x * x);
  y = fminf(fmaxf(y, -12.0f), 12.0f);
  float e = __expf(2.0f * y);
  float th = (e - 1.0f) / (e + 1.0f);
  return 0.5f * x * (1.0f + th);
}
__device__ __forceinline__ float gelu_erf(float x){
  return 0.5f * x * (1.0f + erff(x * 0.7071067811865475f));
}
// unpack a dword holding 2 bf16 into a float2 (lo, hi)
__device__ __forceinline__ f32x2 bf2x2(unsigned int d){
  f32x2 v;
  v.x = __uint_as_float(d << 16);
  v.y = __uint_as_float(d & 0xffff0000u);
  return v;
}
__device__ __forceinline__ f32x2 fma2(f32x2 a, f32x2 b, f32x2 c){
#if defined(__has_builtin)
#if __has_builtin(__builtin_elementwise_fma)
  return __builtin_elementwise_fma(a, b, c);
#else
  return (f32x2){fmaf(a.x, b.x, c.x), fmaf(a.y, b.y, c.y)};
#endif
#else
  return (f32x2){fmaf(a.x, b.x, c.x), fmaf(a.y, b.y, c.y)};
#endif
}

// --------------------------- K2: M_t + ctab precompute ----------------------
// MT[slot=t-1][r][s] (bf16) = sum_{f=1..15} c_f(t) * Wr[(f*64+s)*64 + r]
// ctab[t][f] = c_f(t), t in [1,2048]
__global__ __launch_bounds__(256) void k_mprep(const float* __restrict__ Wr,
    const float* __restrict__ phases, u16* __restrict__ MT, float* __restrict__ ctab){
  int slot = blockIdx.x;                 // tau = slot+1
  float tau = (float)(slot + 1);
  __shared__ float cf[16];
  int tid = threadIdx.x;
  if (tid < 16){
    float c = INV_L * cosf((TWO_PI * INV_L) * tau * (float)tid + TWO_PI * phases[tid]);
    cf[tid] = c;
    ctab[(slot + 1) * 16 + tid] = c;
  }
  __syncthreads();
  int r = tid & 63, s0 = (tid >> 6) * 16;
  float acc[16];
#pragma unroll
  for (int i = 0; i < 16; ++i) acc[i] = 0.0f;
  for (int f = 1; f < 16; ++f){
    float c = cf[f];
    const float* wp = Wr + (f * 64 + s0) * 64 + r;   // coalesced over r (lanes)
#pragma unroll
    for (int i = 0; i < 16; ++i) acc[i] += c * wp[i * 64];
  }
  u16* o = MT + ((size_t)slot * 64 + r) * 64 + s0;
  uint4 p0, p1;
  p0.x = (unsigned)f2bf(acc[0])  | ((unsigned)f2bf(acc[1])  << 16);
  p0.y = (unsigned)f2bf(acc[2])  | ((unsigned)f2bf(acc[3])  << 16);
  p0.z = (unsigned)f2bf(acc[4])  | ((unsigned)f2bf(acc[5])  << 16);
  p0.w = (unsigned)f2bf(acc[6])  | ((unsigned)f2bf(acc[7])  << 16);
  p1.x = (unsigned)f2bf(acc[8])  | ((unsigned)f2bf(acc[9])  << 16);
  p1.y = (unsigned)f2bf(acc[10]) | ((unsigned)f2bf(acc[11]) << 16);
  p1.z = (unsigned)f2bf(acc[12]) | ((unsigned)f2bf(acc[13]) << 16);
  p1.w = (unsigned)f2bf(acc[14]) | ((unsigned)f2bf(acc[15]) << 16);
  ((uint4*)o)[0] = p0;
  ((uint4*)o)[1] = p1;
}

// --------------------------- K1: xstat = x @ Ws[0:128,:] --------------------
__global__ __launch_bounds__(256) void k_xstat(const float* __restrict__ x,
    const float* __restrict__ Ws, float* __restrict__ xstat){
  __shared__ float4 xt4[64 * 32];        // 64 rows x 128 cols
  __shared__ float partial[4][64];
  int tid = threadIdx.x;
  int row0 = blockIdx.x * 64;
  const float4* xg = (const float4*)(x + (size_t)row0 * 128);
  for (int i = tid; i < 2048; i += 256) xt4[i] = xg[i];
  int s = tid & 63, kq = tid >> 6;       // K split 4 x 32
  float wk[32];
#pragma unroll
  for (int j = 0; j < 32; ++j) wk[j] = Ws[(kq * 32 + j) * 64 + s];
  __syncthreads();
  for (int rr = 0; rr < 64; ++rr){
    const float4* xr = &xt4[rr * 32 + kq * 8];
    float a = 0.0f;
#pragma unroll
    for (int j = 0; j < 8; ++j){
      float4 v = xr[j];
      a += v.x * wk[j*4] + v.y * wk[j*4+1] + v.z * wk[j*4+2] + v.w * wk[j*4+3];
    }
    partial[kq][s] = a;
    __syncthreads();
    if (tid < 64)
      xstat[(size_t)(row0 + rr) * 64 + tid] =
        partial[0][tid] + partial[1][tid] + partial[2][tid] + partial[3][tid];
    __syncthreads();
  }
}

// --------------------------- K4b: WoT[n][k] = bf16(Wo[k][n]) ----------------
__global__ __launch_bounds__(256) void k_wot(const float* __restrict__ Wo, u16* __restrict__ WoT){
  __shared__ float tile[64][65];
  int bx = blockIdx.x & 15, by = blockIdx.x >> 4;
  int k0 = bx * 64, n0 = by * 64;
  int tid = threadIdx.x, ln = tid & 63, w = tid >> 6;
#pragma unroll
  for (int i = 0; i < 16; ++i){
    int kk = w * 16 + i;
    tile[kk][ln] = Wo[(size_t)(k0 + kk) * 1024 + n0 + ln];
  }
  __syncthreads();
#pragma unroll
  for (int i = 0; i < 16; ++i){
    int nn = w * 16 + i;
    WoT[(size_t)(n0 + nn) * 1024 + k0 + ln] = f2bf(tile[ln][nn]);
  }
}

// --------------------------- K3: the sequential scan ------------------------
// ONE WAVE per batch element. lane r is the output index for both stages
// (r in stage A, s in stage B). Full 64-long dot products per lane; the
// 64-vector operand (sprev / recur) is read from LDS with same-address
// broadcast reads (conflict-free); no barriers, no shuffles needed.
// MT rows + xstat are prefetched 4 steps ahead in a register ring.
#define MLOAD(MREG, SLOT) { \
  const uint4* _p = mt + (size_t)(SLOT) * 512 + r * 8; \
  _Pragma("unroll") \
  for (int _c = 0; _c < 8; ++_c) MREG[_c] = _p[_c]; \
}

#define SCAN_STEP(T, MREG, XS) { \
  /* ---- stage A: d1 = sprev@M_{T-1}[r,:], d2 = c0 * sprev@Wr0[:,r] ---- */ \
  f32x2 d1a = {0.f,0.f}, d1b = {0.f,0.f}, d2a = {0.f,0.f}, d2b = {0.f,0.f}; \
  _Pragma("unroll") \
  for (int c = 0; c < 8; ++c){ \
    f32x4 s0 = *(const f32x4*)&sprev[c * 8]; \
    f32x4 s1 = *(const f32x4*)&sprev[c * 8 + 4]; \
    uint4 m = MREG[c]; \
    f32x2 sv0 = {s0.x, s0.y}, sv1 = {s0.z, s0.w}; \
    f32x2 sv2 = {s1.x, s1.y}, sv3 = {s1.z, s1.w}; \
    d1a = fma2(sv0, bf2x2(m.x), d1a); \
    d1b = fma2(sv1, bf2x2(m.y), d1b); \
    d1a = fma2(sv2, bf2x2(m.z), d1a); \
    d1b = fma2(sv3, bf2x2(m.w), d1b); \
    d2a = fma2(sv0, wr0c[c*4+0], d2a); \
    d2b = fma2(sv1, wr0c[c*4+1], d2b); \
    d2a = fma2(sv2, wr0c[c*4+2], d2a); \
    d2b = fma2(sv3, wr0c[c*4+3], d2b); \
  } \
  float d1 = (d1a.x + d1a.y) + (d1b.x + d1b.y); \
  float d2 = (d2a.x + d2a.y) + (d2b.x + d2b.y); \
  Pa += d1; \
  float rec = gelu_tanh(Pa + d2 + br_r); \
  recur[r] = rec; \
  /* ---- prefetch for step T+4 (overlaps recur LDS write latency) ---- */ \
  int _ns = ((T) + 2 <= 2047) ? ((T) + 2) : 2047; \
  MLOAD(MREG, _ns); \
  int _nx = ((T) + 3 <= 2047) ? ((T) + 3) : 2047; \
  float _xn = xsp[(size_t)_nx * 64 + r]; \
  /* ---- stage B: a2 = recur@Wsr[:,r] ---- */ \
  f32x2 aa = {0.f,0.f}, ab = {0.f,0.f}; \
  _Pragma("unroll") \
  for (int c = 0; c < 8; ++c){ \
    f32x4 r0 = *(const f32x4*)&recur[c * 8]; \
    f32x4 r1 = *(const f32x4*)&recur[c * 8 + 4]; \
    aa = fma2((f32x2){r0.x, r0.y}, wsrc[c*4+0], aa); \
    ab = fma2((f32x2){r0.z, r0.w}, wsrc[c*4+1], ab); \
    aa = fma2((f32x2){r1.x, r1.y}, wsrc[c*4+2], aa); \
    ab = fma2((f32x2){r1.z, r1.w}, wsrc[c*4+3], ab); \
  } \
  float a2 = (aa.x + aa.y) + (ab.x + ab.y); \
  float stt = gelu_tanh(a2 + XS + bs_s); \
  sprev[r] = stt; \
  sb[(size_t)((T) - 1) * 64 + r] = stt; \
  XS = _xn; \
}

__global__ __launch_bounds__(64) void k_scan(
    const float* __restrict__ Wr, const float* __restrict__ br,
    const float* __restrict__ Ws, const float* __restrict__ bs,
    const float* __restrict__ phases, const float* __restrict__ xstat,
    const u16* __restrict__ MT, float* __restrict__ statsbuf){
  int b = blockIdx.x;
  int r = threadIdx.x;                   // 0..63
  __shared__ __align__(16) float sprev[64];
  __shared__ __align__(16) float recur[64];
  float c0 = INV_L * cosf(TWO_PI * phases[0]);
  // resident weight columns (c0 folded into Wr0 column)
  f32x2 wr0c[32], wsrc[32];
#pragma unroll
  for (int k = 0; k < 32; ++k){
    wr0c[k].x = c0 * Wr[(2 * k) * 64 + r];
    wr0c[k].y = c0 * Wr[(2 * k + 1) * 64 + r];
    wsrc[k].x = Ws[(128 + 2 * k) * 64 + r];
    wsrc[k].y = Ws[(128 + 2 * k + 1) * 64 + r];
  }
  float br_r = br[r];
  float bs_s = bs[r];
  float Pa = 0.0f;
  sprev[r] = 0.0f;
  __syncthreads();
  const uint4* mt = (const uint4*)MT;    // 512 uint4 per slot; lane row = 8 uint4
  const float* xsp = xstat + (size_t)b * 2048 * 64;
  float* sb = statsbuf + (size_t)b * 2048 * 64;
  // 4-deep ring: step t uses M slot max(t-2,0) and xstat index t-1
  uint4 mA[8], mB[8], mC[8], mD[8];
  float xsA, xsB, xsC, xsD;
  MLOAD(mA, 0); xsA = xsp[0 * 64 + r];
  MLOAD(mB, 0); xsB = xsp[1 * 64 + r];
  MLOAD(mC, 1); xsC = xsp[2 * 64 + r];
  MLOAD(mD, 2); xsD = xsp[3 * 64 + r];
  for (int t = 1; t <= 2048; t += 4){
    SCAN_STEP(t,     mA, xsA);
    SCAN_STEP(t + 1, mB, xsB);
    SCAN_STEP(t + 2, mC, xsC);
    SCAN_STEP(t + 3, mD, xsD);
  }
}

// --------------------------- K4: state materialization (bf16) ---------------
// state[b,t,f*64+s]: f>=1 cumsum of c_f(t)*stats; f=0 current term only.
__global__ __launch_bounds__(256) void k_state(const float* __restrict__ statsbuf,
    const float* __restrict__ ctab, u16* __restrict__ stateA){
  int g = blockIdx.x * 256 + threadIdx.x;       // [0, 32768)
  int s = g & 63, f = (g >> 6) & 15, b = g >> 10;
  const float* sp = statsbuf + (size_t)b * 2048 * 64 + s;
  u16* op = stateA + (size_t)b * 2048 * 1024 + f * 64 + s;
  float acc = 0.0f;
  const bool f0 = (f == 0);
  for (int t0 = 0; t0 < 2048; t0 += 8){
    float sv[8], cv[8];
#pragma unroll
    for (int i = 0; i < 8; ++i) sv[i] = sp[(size_t)(t0 + i) * 64];
#pragma unroll
    for (int i = 0; i < 8; ++i) cv[i] = ctab[(t0 + i + 1) * 16 + f];
#pragma unroll
    for (int i = 0; i < 8; ++i){
      acc = f0 ? (cv[i] * sv[i]) : fmaf(cv[i], sv[i], acc);
      op[(size_t)(t0 + i) * 1024] = f2bf(acc);
    }
  }
}

// --------------------------- K5: out = gelu(state @ Wo + bo) ----------------
// bf16 MFMA GEMM, 128x128 tile, 4 waves, 16x16x32, BT layout in LDS.
__global__ __launch_bounds__(256) void k_gemm(const u16* __restrict__ A,
    const u16* __restrict__ Bt, const float* __restrict__ bo, float* __restrict__ out){
  int nt = blockIdx.x & 7, mt = blockIdx.x >> 3;
  int m0 = mt * 128, n0 = nt * 128;
  __shared__ __align__(16) u16 As[128 * 32];
  __shared__ __align__(16) u16 Bs[128 * 32];
  int tid = threadIdx.x;
  int w = tid >> 6, l = tid & 63;
  int mh = (w & 1) * 64, nh = (w >> 1) * 64;
  int lr = l & 15, lq = l >> 4;
  f32x4 acc[4][4] = {};
  for (int k0 = 0; k0 < 1024; k0 += 32){
    int c = tid;
#pragma unroll
    for (int rr = 0; rr < 2; ++rr, c += 256){
      int row = c >> 2, qq = c & 3;
      *((uint4*)&As[row * 32 + qq * 8]) = *(const uint4*)(A  + (size_t)(m0 + row) * 1024 + k0 + qq * 8);
      *((uint4*)&Bs[row * 32 + qq * 8]) = *(const uint4*)(Bt + (size_t)(n0 + row) * 1024 + k0 + qq * 8);
    }
    __syncthreads();
    bf16x8 af[4], bfr[4];
#pragma unroll
    for (int i = 0; i < 4; ++i) af[i]  = *(const bf16x8*)&As[(mh + i * 16 + lr) * 32 + lq * 8];
#pragma unroll
    for (int i = 0; i < 4; ++i) bfr[i] = *(const bf16x8*)&Bs[(nh + i * 16 + lr) * 32 + lq * 8];
#pragma unroll
    for (int i = 0; i < 4; ++i)
#pragma unroll
      for (int j = 0; j < 4; ++j)
        acc[i][j] = __builtin_amdgcn_mfma_f32_16x16x32_bf16(af[i], bfr[j], acc[i][j], 0, 0, 0);
    __syncthreads();
  }
#pragma unroll
  for (int i = 0; i < 4; ++i){
#pragma unroll
    for (int j = 0; j < 4; ++j){
      int n = n0 + nh + j * 16 + lr;
      float bias = bo[n];
#pragma unroll
      for (int rg = 0; rg < 4; ++rg){
        int m = m0 + mh + i * 16 + lq * 4 + rg;
        out[(size_t)m * 1024 + n] = gelu_erf(acc[i][j][rg] + bias);
      }
    }
  }
}

// --------------------------- launcher ---------------------------------------
extern "C" void kernel_launch(void* const* d_in, const int* in_sizes, int n_in,
                              void* d_out, int out_size, void* d_ws, size_t ws_size,
                              hipStream_t stream){
  const float* x  = (const float*)d_in[0];
  const float* Wr = (const float*)d_in[1];
  const float* br = (const float*)d_in[2];
  const float* Ws = (const float*)d_in[3];
  const float* bs = (const float*)d_in[4];
  const float* Wo = (const float*)d_in[5];
  const float* bo = (const float*)d_in[6];
  const float* ph = (const float*)d_in[7];
  float* out = (float*)d_out;

  char* wp = (char*)d_ws;
  float* xstat    = (float*)(wp);                     // 16 MB: 65536 x 64 f32
  float* statsbuf = (float*)(wp + 16777216);          // 16 MB: 32 x 2048 x 64 f32
  u16*   MT       = (u16*)  (wp + 33554432);          // 16 MB: 2048 x 64 x 64 bf16
  float* ctab     = (float*)(wp + 50331648);          // 128 KB: 2049 x 16 f32
  u16*   WoT      = (u16*)  (wp + 50593792);          // 2 MB: 1024 x 1024 bf16
  u16*   stateA   = (u16*)  (wp + 52690944);          // 128 MB: 65536 x 1024 bf16

  hipLaunchKernelGGL(k_mprep, dim3(2048), dim3(256), 0, stream, Wr, ph, MT, ctab);
  hipLaunchKernelGGL(k_xstat, dim3(1024), dim3(256), 0, stream, x, Ws, xstat);
  hipLaunchKernelGGL(k_wot,   dim3(256),  dim3(256), 0, stream, Wo, WoT);
  hipLaunchKernelGGL(k_scan,  dim3(32),   dim3(64),  0, stream, Wr, br, Ws, bs, ph, xstat, MT, statsbuf);
  hipLaunchKernelGGL(k_state, dim3(128),  dim3(256), 0, stream, statsbuf, ctab, stateA);
  hipLaunchKernelGGL(k_gemm,  dim3(4096), dim3(256), 0, stream, stateA, WoT, bo, out);
}

// Round 3
// 2812.664 us; speedup vs baseline: 1.0851x; 1.0851x over previous
//
#include <hip/hip_runtime.h>
#include <math.h>

// ---------------------------------------------------------------------------
// FRU cell, decomposed:
//   state[f,s](t) = sum_{tau<=t} c_f(tau)*stats[s](tau)   (f>=1; f=0: current only)
//   c_f(t) = (1/L)*cos((2pi/L)*t*f + 2pi*phases[f])
// Scan only carries: Pa[r] = state_acc@Wr  (64 floats) and stats(t-1) (64 floats).
//   recur(t)  = gelu(Pa(t-1) + c0*stats(t-1)@Wr0 + br)
//   stats(t)  = gelu(xstat[b,t] + recur@Wsr + bs)
//   Pa(t)     = Pa(t-1) + stats(t)@M_t,  M_t precomputed (bf16, streamed)
// k_scan v3: ONE WAVE per batch, LANE-INTERLEAVED MT layout:
//   MT4[slot][c][lane] (uint4) so each of the 8 per-step global loads is a
//   contiguous 1 KB wave transaction (v2's per-lane-row layout was stride-128B
//   -> 64 cache lines per instruction -> ~2000 cy/step of TA stall).
//   No barriers/shuffles: full 64-dots per lane, sprev/recur via LDS
//   broadcast reads; 4-deep register ring prefetch; packed f32 FMAs.
// Then: state materialized bf16 (cumsum over t), out = gelu(state@Wo + bo) as
// one big bf16 MFMA GEMM.
// ---------------------------------------------------------------------------

#define TWO_PI 6.283185307179586f
#define INV_L  (1.0f/2048.0f)

typedef unsigned short u16;
typedef __attribute__((ext_vector_type(8))) short bf16x8;   // 8 bf16 = 4 VGPRs
typedef __attribute__((ext_vector_type(4))) float f32x4;
typedef __attribute__((ext_vector_type(2))) float f32x2;

__device__ __forceinline__ float bf2f(u16 u){ return __uint_as_float(((unsigned int)u) << 16); }
__device__ __forceinline__ u16 f2bf(float x){
  unsigned int u = __float_as_uint(x);
  u += 0x7FFFu + ((u >> 16) & 1u);           // round-to-nearest-even
  return (u16)(u >> 16);
}
__device__ __forceinline__ float gelu_tanh(float x){
  // tanh-approx gelu: error <3e-4 abs; attenuated ~50x through the (1/L) cumsum.
  float y = 0.7978845608028654f * x * (1.0f + 0.044715f * x * x);
  y = fminf(fmaxf(y, -12.0f), 12.0f);
  float e = __expf(2.0f * y);
  float th = (e - 1.0f) / (e + 1.0f);
  return 0.5f * x * (1.0f + th);
}
__device__ __forceinline__ float gelu_erf(float x){
  return 0.5f * x * (1.0f + erff(x * 0.7071067811865475f));
}
// unpack a dword holding 2 bf16 into a float2 (lo, hi)
__device__ __forceinline__ f32x2 bf2x2(unsigned int d){
  f32x2 v;
  v.x = __uint_as_float(d << 16);
  v.y = __uint_as_float(d & 0xffff0000u);
  return v;
}
__device__ __forceinline__ f32x2 fma2(f32x2 a, f32x2 b, f32x2 c){
#if defined(__has_builtin)
#if __has_builtin(__builtin_elementwise_fma)
  return __builtin_elementwise_fma(a, b, c);
#else
  return (f32x2){fmaf(a.x, b.x, c.x), fmaf(a.y, b.y, c.y)};
#endif
#else
  return (f32x2){fmaf(a.x, b.x, c.x), fmaf(a.y, b.y, c.y)};
#endif
}

// --------------------------- K2: M_t + ctab precompute ----------------------
// M[r][s](t) = sum_{f=1..15} c_f(t) * Wr[(f*64+s)*64 + r]
// Lane-interleaved store: MT4[slot*512 + (s>>3)*64 + r] (uint4 units) holds
// M[r][8c..8c+7] as 8 bf16 -> k_scan's per-step loads are contiguous 1 KB.
// ctab[t][f] = c_f(t), t in [1,2048]
__global__ __launch_bounds__(256) void k_mprep(const float* __restrict__ Wr,
    const float* __restrict__ phases, u16* __restrict__ MT, float* __restrict__ ctab){
  int slot = blockIdx.x;                 // tau = slot+1
  float tau = (float)(slot + 1);
  __shared__ float cf[16];
  int tid = threadIdx.x;
  if (tid < 16){
    float c = INV_L * cosf((TWO_PI * INV_L) * tau * (float)tid + TWO_PI * phases[tid]);
    cf[tid] = c;
    ctab[(slot + 1) * 16 + tid] = c;
  }
  __syncthreads();
  int r = tid & 63, s0 = (tid >> 6) * 16;
  float acc[16];
#pragma unroll
  for (int i = 0; i < 16; ++i) acc[i] = 0.0f;
  for (int f = 1; f < 16; ++f){
    float c = cf[f];
    const float* wp = Wr + (f * 64 + s0) * 64 + r;   // coalesced over r (lanes)
#pragma unroll
    for (int i = 0; i < 16; ++i) acc[i] += c * wp[i * 64];
  }
  uint4 p0, p1;
  p0.x = (unsigned)f2bf(acc[0])  | ((unsigned)f2bf(acc[1])  << 16);
  p0.y = (unsigned)f2bf(acc[2])  | ((unsigned)f2bf(acc[3])  << 16);
  p0.z = (unsigned)f2bf(acc[4])  | ((unsigned)f2bf(acc[5])  << 16);
  p0.w = (unsigned)f2bf(acc[6])  | ((unsigned)f2bf(acc[7])  << 16);
  p1.x = (unsigned)f2bf(acc[8])  | ((unsigned)f2bf(acc[9])  << 16);
  p1.y = (unsigned)f2bf(acc[10]) | ((unsigned)f2bf(acc[11]) << 16);
  p1.z = (unsigned)f2bf(acc[12]) | ((unsigned)f2bf(acc[13]) << 16);
  p1.w = (unsigned)f2bf(acc[14]) | ((unsigned)f2bf(acc[15]) << 16);
  uint4* o4 = (uint4*)MT + (size_t)slot * 512 + r;
  int c0 = s0 >> 3;                       // chunk index of acc[0..7]
  o4[(size_t)c0 * 64]       = p0;         // lanes r consecutive -> coalesced
  o4[(size_t)(c0 + 1) * 64] = p1;
}

// --------------------------- K1: xstat = x @ Ws[0:128,:] --------------------
__global__ __launch_bounds__(256) void k_xstat(const float* __restrict__ x,
    const float* __restrict__ Ws, float* __restrict__ xstat){
  __shared__ float4 xt4[64 * 32];        // 64 rows x 128 cols
  __shared__ float partial[4][64];
  int tid = threadIdx.x;
  int row0 = blockIdx.x * 64;
  const float4* xg = (const float4*)(x + (size_t)row0 * 128);
  for (int i = tid; i < 2048; i += 256) xt4[i] = xg[i];
  int s = tid & 63, kq = tid >> 6;       // K split 4 x 32
  float wk[32];
#pragma unroll
  for (int j = 0; j < 32; ++j) wk[j] = Ws[(kq * 32 + j) * 64 + s];
  __syncthreads();
  for (int rr = 0; rr < 64; ++rr){
    const float4* xr = &xt4[rr * 32 + kq * 8];
    float a = 0.0f;
#pragma unroll
    for (int j = 0; j < 8; ++j){
      float4 v = xr[j];
      a += v.x * wk[j*4] + v.y * wk[j*4+1] + v.z * wk[j*4+2] + v.w * wk[j*4+3];
    }
    partial[kq][s] = a;
    __syncthreads();
    if (tid < 64)
      xstat[(size_t)(row0 + rr) * 64 + tid] =
        partial[0][tid] + partial[1][tid] + partial[2][tid] + partial[3][tid];
    __syncthreads();
  }
}

// --------------------------- K4b: WoT[n][k] = bf16(Wo[k][n]) ----------------
__global__ __launch_bounds__(256) void k_wot(const float* __restrict__ Wo, u16* __restrict__ WoT){
  __shared__ float tile[64][65];
  int bx = blockIdx.x & 15, by = blockIdx.x >> 4;
  int k0 = bx * 64, n0 = by * 64;
  int tid = threadIdx.x, ln = tid & 63, w = tid >> 6;
#pragma unroll
  for (int i = 0; i < 16; ++i){
    int kk = w * 16 + i;
    tile[kk][ln] = Wo[(size_t)(k0 + kk) * 1024 + n0 + ln];
  }
  __syncthreads();
#pragma unroll
  for (int i = 0; i < 16; ++i){
    int nn = w * 16 + i;
    WoT[(size_t)(n0 + nn) * 1024 + k0 + ln] = f2bf(tile[ln][nn]);
  }
}

// --------------------------- K3: the sequential scan ------------------------
// ONE WAVE per batch element. lane r is the output index for both stages
// (r in stage A, s in stage B). Full 64-long dot products per lane; the
// 64-vector operand (sprev / recur) is read from LDS with same-address
// broadcast reads (conflict-free); no barriers, no shuffles needed.
// MT chunks + xstat are prefetched 4 steps ahead in a register ring.
// MT layout: uint4 index slot*512 + c*64 + r  (contiguous 1 KB per load instr)
#define MLOAD(MREG, SLOT) { \
  const uint4* _p = mt + (size_t)(SLOT) * 512 + r; \
  _Pragma("unroll") \
  for (int _c = 0; _c < 8; ++_c) MREG[_c] = _p[_c * 64]; \
}

#define SCAN_STEP(T, MREG, XS) { \
  /* ---- stage A: d1 = sprev@M_{T-1}[r,:], d2 = c0 * sprev@Wr0[:,r] ---- */ \
  f32x2 d1a = {0.f,0.f}, d1b = {0.f,0.f}, d2a = {0.f,0.f}, d2b = {0.f,0.f}; \
  _Pragma("unroll") \
  for (int c = 0; c < 8; ++c){ \
    f32x4 s0 = *(const f32x4*)&sprev[c * 8]; \
    f32x4 s1 = *(const f32x4*)&sprev[c * 8 + 4]; \
    uint4 m = MREG[c]; \
    f32x2 sv0 = {s0.x, s0.y}, sv1 = {s0.z, s0.w}; \
    f32x2 sv2 = {s1.x, s1.y}, sv3 = {s1.z, s1.w}; \
    d1a = fma2(sv0, bf2x2(m.x), d1a); \
    d1b = fma2(sv1, bf2x2(m.y), d1b); \
    d1a = fma2(sv2, bf2x2(m.z), d1a); \
    d1b = fma2(sv3, bf2x2(m.w), d1b); \
    d2a = fma2(sv0, wr0c[c*4+0], d2a); \
    d2b = fma2(sv1, wr0c[c*4+1], d2b); \
    d2a = fma2(sv2, wr0c[c*4+2], d2a); \
    d2b = fma2(sv3, wr0c[c*4+3], d2b); \
  } \
  float d1 = (d1a.x + d1a.y) + (d1b.x + d1b.y); \
  float d2 = (d2a.x + d2a.y) + (d2b.x + d2b.y); \
  Pa += d1; \
  float rec = gelu_tanh(Pa + d2 + br_r); \
  recur[r] = rec; \
  /* ---- prefetch for step T+4 (overlaps recur LDS write latency) ---- */ \
  int _ns = ((T) + 2 <= 2047) ? ((T) + 2) : 2047; \
  MLOAD(MREG, _ns); \
  int _nx = ((T) + 3 <= 2047) ? ((T) + 3) : 2047; \
  float _xn = xsp[(size_t)_nx * 64 + r]; \
  /* ---- stage B: a2 = recur@Wsr[:,r] ---- */ \
  f32x2 aa = {0.f,0.f}, ab = {0.f,0.f}; \
  _Pragma("unroll") \
  for (int c = 0; c < 8; ++c){ \
    f32x4 r0 = *(const f32x4*)&recur[c * 8]; \
    f32x4 r1 = *(const f32x4*)&recur[c * 8 + 4]; \
    aa = fma2((f32x2){r0.x, r0.y}, wsrc[c*4+0], aa); \
    ab = fma2((f32x2){r0.z, r0.w}, wsrc[c*4+1], ab); \
    aa = fma2((f32x2){r1.x, r1.y}, wsrc[c*4+2], aa); \
    ab = fma2((f32x2){r1.z, r1.w}, wsrc[c*4+3], ab); \
  } \
  float a2 = (aa.x + aa.y) + (ab.x + ab.y); \
  float stt = gelu_tanh(a2 + XS + bs_s); \
  sprev[r] = stt; \
  sb[(size_t)((T) - 1) * 64 + r] = stt; \
  XS = _xn; \
}

__global__ __launch_bounds__(64) void k_scan(
    const float* __restrict__ Wr, const float* __restrict__ br,
    const float* __restrict__ Ws, const float* __restrict__ bs,
    const float* __restrict__ phases, const float* __restrict__ xstat,
    const u16* __restrict__ MT, float* __restrict__ statsbuf){
  int b = blockIdx.x;
  int r = threadIdx.x;                   // 0..63
  __shared__ __align__(16) float sprev[64];
  __shared__ __align__(16) float recur[64];
  float c0 = INV_L * cosf(TWO_PI * phases[0]);
  // resident weight columns (c0 folded into Wr0 column)
  f32x2 wr0c[32], wsrc[32];
#pragma unroll
  for (int k = 0; k < 32; ++k){
    wr0c[k].x = c0 * Wr[(2 * k) * 64 + r];
    wr0c[k].y = c0 * Wr[(2 * k + 1) * 64 + r];
    wsrc[k].x = Ws[(128 + 2 * k) * 64 + r];
    wsrc[k].y = Ws[(128 + 2 * k + 1) * 64 + r];
  }
  float br_r = br[r];
  float bs_s = bs[r];
  float Pa = 0.0f;
  sprev[r] = 0.0f;
  __syncthreads();
  const uint4* mt = (const uint4*)MT;    // 512 uint4 per slot, lane-interleaved
  const float* xsp = xstat + (size_t)b * 2048 * 64;
  float* sb = statsbuf + (size_t)b * 2048 * 64;
  // 4-deep ring: step t uses M slot max(t-2,0) and xstat index t-1
  uint4 mA[8], mB[8], mC[8], mD[8];
  float xsA, xsB, xsC, xsD;
  MLOAD(mA, 0); xsA = xsp[0 * 64 + r];
  MLOAD(mB, 0); xsB = xsp[1 * 64 + r];
  MLOAD(mC, 1); xsC = xsp[2 * 64 + r];
  MLOAD(mD, 2); xsD = xsp[3 * 64 + r];
  for (int t = 1; t <= 2048; t += 4){
    SCAN_STEP(t,     mA, xsA);
    SCAN_STEP(t + 1, mB, xsB);
    SCAN_STEP(t + 2, mC, xsC);
    SCAN_STEP(t + 3, mD, xsD);
  }
}

// --------------------------- K4: state materialization (bf16) ---------------
// state[b,t,f*64+s]: f>=1 cumsum of c_f(t)*stats; f=0 current term only.
__global__ __launch_bounds__(256) void k_state(const float* __restrict__ statsbuf,
    const float* __restrict__ ctab, u16* __restrict__ stateA){
  int g = blockIdx.x * 256 + threadIdx.x;       // [0, 32768)
  int s = g & 63, f = (g >> 6) & 15, b = g >> 10;
  const float* sp = statsbuf + (size_t)b * 2048 * 64 + s;
  u16* op = stateA + (size_t)b * 2048 * 1024 + f * 64 + s;
  float acc = 0.0f;
  const bool f0 = (f == 0);
  for (int t0 = 0; t0 < 2048; t0 += 8){
    float sv[8], cv[8];
#pragma unroll
    for (int i = 0; i < 8; ++i) sv[i] = sp[(size_t)(t0 + i) * 64];
#pragma unroll
    for (int i = 0; i < 8; ++i) cv[i] = ctab[(t0 + i + 1) * 16 + f];
#pragma unroll
    for (int i = 0; i < 8; ++i){
      acc = f0 ? (cv[i] * sv[i]) : fmaf(cv[i], sv[i], acc);
      op[(size_t)(t0 + i) * 1024] = f2bf(acc);
    }
  }
}

// --------------------------- K5: out = gelu(state @ Wo + bo) ----------------
// bf16 MFMA GEMM, 128x128 tile, 4 waves, 16x16x32, BT layout in LDS.
__global__ __launch_bounds__(256) void k_gemm(const u16* __restrict__ A,
    const u16* __restrict__ Bt, const float* __restrict__ bo, float* __restrict__ out){
  int nt = blockIdx.x & 7, mt = blockIdx.x >> 3;
  int m0 = mt * 128, n0 = nt * 128;
  __shared__ __align__(16) u16 As[128 * 32];
  __shared__ __align__(16) u16 Bs[128 * 32];
  int tid = threadIdx.x;
  int w = tid >> 6, l = tid & 63;
  int mh = (w & 1) * 64, nh = (w >> 1) * 64;
  int lr = l & 15, lq = l >> 4;
  f32x4 acc[4][4] = {};
  for (int k0 = 0; k0 < 1024; k0 += 32){
    int c = tid;
#pragma unroll
    for (int rr = 0; rr < 2; ++rr, c += 256){
      int row = c >> 2, qq = c & 3;
      *((uint4*)&As[row * 32 + qq * 8]) = *(const uint4*)(A  + (size_t)(m0 + row) * 1024 + k0 + qq * 8);
      *((uint4*)&Bs[row * 32 + qq * 8]) = *(const uint4*)(Bt + (size_t)(n0 + row) * 1024 + k0 + qq * 8);
    }
    __syncthreads();
    bf16x8 af[4], bfr[4];
#pragma unroll
    for (int i = 0; i < 4; ++i) af[i]  = *(const bf16x8*)&As[(mh + i * 16 + lr) * 32 + lq * 8];
#pragma unroll
    for (int i = 0; i < 4; ++i) bfr[i] = *(const bf16x8*)&Bs[(nh + i * 16 + lr) * 32 + lq * 8];
#pragma unroll
    for (int i = 0; i < 4; ++i)
#pragma unroll
      for (int j = 0; j < 4; ++j)
        acc[i][j] = __builtin_amdgcn_mfma_f32_16x16x32_bf16(af[i], bfr[j], acc[i][j], 0, 0, 0);
    __syncthreads();
  }
#pragma unroll
  for (int i = 0; i < 4; ++i){
#pragma unroll
    for (int j = 0; j < 4; ++j){
      int n = n0 + nh + j * 16 + lr;
      float bias = bo[n];
#pragma unroll
      for (int rg = 0; rg < 4; ++rg){
        int m = m0 + mh + i * 16 + lq * 4 + rg;
        out[(size_t)m * 1024 + n] = gelu_erf(acc[i][j][rg] + bias);
      }
    }
  }
}

// --------------------------- launcher ---------------------------------------
extern "C" void kernel_launch(void* const* d_in, const int* in_sizes, int n_in,
                              void* d_out, int out_size, void* d_ws, size_t ws_size,
                              hipStream_t stream){
  const float* x  = (const float*)d_in[0];
  const float* Wr = (const float*)d_in[1];
  const float* br = (const float*)d_in[2];
  const float* Ws = (const float*)d_in[3];
  const float* bs = (const float*)d_in[4];
  const float* Wo = (const float*)d_in[5];
  const float* bo = (const float*)d_in[6];
  const float* ph = (const float*)d_in[7];
  float* out = (float*)d_out;

  char* wp = (char*)d_ws;
  float* xstat    = (float*)(wp);                     // 16 MB: 65536 x 64 f32
  float* statsbuf = (float*)(wp + 16777216);          // 16 MB: 32 x 2048 x 64 f32
  u16*   MT       = (u16*)  (wp + 33554432);          // 16 MB: 2048 x 64 x 64 bf16
  float* ctab     = (float*)(wp + 50331648);          // 128 KB: 2049 x 16 f32
  u16*   WoT      = (u16*)  (wp + 50593792);          // 2 MB: 1024 x 1024 bf16
  u16*   stateA   = (u16*)  (wp + 52690944);          // 128 MB: 65536 x 1024 bf16

  hipLaunchKernelGGL(k_mprep, dim3(2048), dim3(256), 0, stream, Wr, ph, MT, ctab);
  hipLaunchKernelGGL(k_xstat, dim3(1024), dim3(256), 0, stream, x, Ws, xstat);
  hipLaunchKernelGGL(k_wot,   dim3(256),  dim3(256), 0, stream, Wo, WoT);
  hipLaunchKernelGGL(k_scan,  dim3(32),   dim3(64),  0, stream, Wr, br, Ws, bs, ph, xstat, MT, statsbuf);
  hipLaunchKernelGGL(k_state, dim3(128),  dim3(256), 0, stream, statsbuf, ctab, stateA);
  hipLaunchKernelGGL(k_gemm,  dim3(4096), dim3(256), 0, stream, stateA, WoT, bo, out);
}

// Round 4
// 2121.504 us; speedup vs baseline: 1.4386x; 1.3258x over previous
//
#include <hip/hip_runtime.h>
#include <math.h>

// ---------------------------------------------------------------------------
// FRU cell, decomposed:
//   state[f,s](t) = sum_{tau<=t} c_f(tau)*stats[s](tau)   (f>=1; f=0: current only)
//   c_f(t) = (1/L)*cos((2pi/L)*t*f + 2pi*phases[f])
// Scan only carries: Pa[r] = state_acc@Wr  (64 floats) and stats(t-1) (64 floats).
//   recur(t)  = gelu(Pa(t-1) + c0*stats(t-1)@Wr0 + br)
//   stats(t)  = gelu(xstat[b,t] + recur@Wsr + bs)
//   Pa(t)     = Pa(t-1) + stats(t)@M_t,  M_t precomputed (bf16, streamed)
// k_scan v4: v1's 4-wave split (256 thr: idx=out, q=K-quarter, quad-shuffle
// reduce) + RAW barriers (s_waitcnt lgkmcnt(0); s_barrier — no vmcnt drain,
// so MT/xstat prefetch stays in flight across barriers; __syncthreads would
// drain vmcnt(0) and expose LLC latency every half-step) + 2-step register
// ring prefetch loaded DIRECTLY into ring regs after last use (no copies ->
// no early vmcnt waits). ~90 VGPR so the scheduler has no pressure reason to
// sink the prefetch (v3's 290-reg demand collapsed the ring to 0-deep).
// Then: state materialized bf16 (cumsum over t), out = gelu(state@Wo + bo) as
// one big bf16 MFMA GEMM.
// ---------------------------------------------------------------------------

#define TWO_PI 6.283185307179586f
#define INV_L  (1.0f/2048.0f)

typedef unsigned short u16;
typedef __attribute__((ext_vector_type(8))) short bf16x8;   // 8 bf16 = 4 VGPRs
typedef __attribute__((ext_vector_type(4))) float f32x4;

__device__ __forceinline__ float bf2f(u16 u){ return __uint_as_float(((unsigned int)u) << 16); }
__device__ __forceinline__ u16 f2bf(float x){
  unsigned int u = __float_as_uint(x);
  u += 0x7FFFu + ((u >> 16) & 1u);           // round-to-nearest-even
  return (u16)(u >> 16);
}
__device__ __forceinline__ float gelu_tanh(float x){
  // tanh-approx gelu: error <3e-4 abs; attenuated ~50x through the (1/L) cumsum.
  float y = 0.7978845608028654f * x * (1.0f + 0.044715f * x * x);
  y = fminf(fmaxf(y, -12.0f), 12.0f);
  float e = __expf(2.0f * y);
  float th = (e - 1.0f) / (e + 1.0f);
  return 0.5f * x * (1.0f + th);
}
__device__ __forceinline__ float gelu_erf(float x){
  return 0.5f * x * (1.0f + erff(x * 0.7071067811865475f));
}

// --------------------------- K2: M_t + ctab precompute ----------------------
// MT[slot=t-1][r][s] (bf16) = sum_{f=1..15} c_f(t) * Wr[(f*64+s)*64 + r]
// ctab[t][f] = c_f(t), t in [1,2048]
__global__ __launch_bounds__(256) void k_mprep(const float* __restrict__ Wr,
    const float* __restrict__ phases, u16* __restrict__ MT, float* __restrict__ ctab){
  int slot = blockIdx.x;                 // tau = slot+1
  float tau = (float)(slot + 1);
  __shared__ float cf[16];
  int tid = threadIdx.x;
  if (tid < 16){
    float c = INV_L * cosf((TWO_PI * INV_L) * tau * (float)tid + TWO_PI * phases[tid]);
    cf[tid] = c;
    ctab[(slot + 1) * 16 + tid] = c;
  }
  __syncthreads();
  int r = tid & 63, s0 = (tid >> 6) * 16;
  float acc[16];
#pragma unroll
  for (int i = 0; i < 16; ++i) acc[i] = 0.0f;
  for (int f = 1; f < 16; ++f){
    float c = cf[f];
    const float* wp = Wr + (f * 64 + s0) * 64 + r;   // coalesced over r (lanes)
#pragma unroll
    for (int i = 0; i < 16; ++i) acc[i] += c * wp[i * 64];
  }
  u16* o = MT + ((size_t)slot * 64 + r) * 64 + s0;
  uint4 p0, p1;
  p0.x = (unsigned)f2bf(acc[0])  | ((unsigned)f2bf(acc[1])  << 16);
  p0.y = (unsigned)f2bf(acc[2])  | ((unsigned)f2bf(acc[3])  << 16);
  p0.z = (unsigned)f2bf(acc[4])  | ((unsigned)f2bf(acc[5])  << 16);
  p0.w = (unsigned)f2bf(acc[6])  | ((unsigned)f2bf(acc[7])  << 16);
  p1.x = (unsigned)f2bf(acc[8])  | ((unsigned)f2bf(acc[9])  << 16);
  p1.y = (unsigned)f2bf(acc[10]) | ((unsigned)f2bf(acc[11]) << 16);
  p1.z = (unsigned)f2bf(acc[12]) | ((unsigned)f2bf(acc[13]) << 16);
  p1.w = (unsigned)f2bf(acc[14]) | ((unsigned)f2bf(acc[15]) << 16);
  ((uint4*)o)[0] = p0;
  ((uint4*)o)[1] = p1;
}

// --------------------------- K1: xstat = x @ Ws[0:128,:] --------------------
__global__ __launch_bounds__(256) void k_xstat(const float* __restrict__ x,
    const float* __restrict__ Ws, float* __restrict__ xstat){
  __shared__ float4 xt4[64 * 32];        // 64 rows x 128 cols
  __shared__ float partial[4][64];
  int tid = threadIdx.x;
  int row0 = blockIdx.x * 64;
  const float4* xg = (const float4*)(x + (size_t)row0 * 128);
  for (int i = tid; i < 2048; i += 256) xt4[i] = xg[i];
  int s = tid & 63, kq = tid >> 6;       // K split 4 x 32
  float wk[32];
#pragma unroll
  for (int j = 0; j < 32; ++j) wk[j] = Ws[(kq * 32 + j) * 64 + s];
  __syncthreads();
  for (int rr = 0; rr < 64; ++rr){
    const float4* xr = &xt4[rr * 32 + kq * 8];
    float a = 0.0f;
#pragma unroll
    for (int j = 0; j < 8; ++j){
      float4 v = xr[j];
      a += v.x * wk[j*4] + v.y * wk[j*4+1] + v.z * wk[j*4+2] + v.w * wk[j*4+3];
    }
    partial[kq][s] = a;
    __syncthreads();
    if (tid < 64)
      xstat[(size_t)(row0 + rr) * 64 + tid] =
        partial[0][tid] + partial[1][tid] + partial[2][tid] + partial[3][tid];
    __syncthreads();
  }
}

// --------------------------- K4b: WoT[n][k] = bf16(Wo[k][n]) ----------------
__global__ __launch_bounds__(256) void k_wot(const float* __restrict__ Wo, u16* __restrict__ WoT){
  __shared__ float tile[64][65];
  int bx = blockIdx.x & 15, by = blockIdx.x >> 4;
  int k0 = bx * 64, n0 = by * 64;
  int tid = threadIdx.x, ln = tid & 63, w = tid >> 6;
#pragma unroll
  for (int i = 0; i < 16; ++i){
    int kk = w * 16 + i;
    tile[kk][ln] = Wo[(size_t)(k0 + kk) * 1024 + n0 + ln];
  }
  __syncthreads();
#pragma unroll
  for (int i = 0; i < 16; ++i){
    int nn = w * 16 + i;
    WoT[(size_t)(n0 + nn) * 1024 + k0 + ln] = f2bf(tile[ln][nn]);
  }
}

// --------------------------- K3: the sequential scan ------------------------
// One workgroup per batch element. 256 threads: idx = w*16 + (l>>2) is the
// output index (r in stage A, s in stage B); q = l&3 splits K=64 into 4x16,
// reduced with __shfl_xor within the quad (no cross-wave shuffle).
// RAW barrier: waits DS only; global prefetch stays outstanding across it.
#define BARRIER_LG() asm volatile("s_waitcnt lgkmcnt(0)\n\ts_barrier" ::: "memory")

// One scan step. Consumes ring regs (M0,M1,XS); reloads them (for step T+2)
// DIRECTLY (no copies) right after their last use.
#define SSTEP(T, M0, M1, XS) { \
  union { uint4 v; u16 h[8]; } ua, ub; \
  ua.v = M0; ub.v = M1; \
  float mv[16]; \
  _Pragma("unroll") \
  for (int i = 0; i < 8; ++i){ mv[i] = bf2f(ua.h[i]); mv[8 + i] = bf2f(ub.h[i]); } \
  float d1 = 0.0f, d2 = 0.0f; \
  _Pragma("unroll") \
  for (int j = 0; j < 4; ++j){ \
    float4 sv = sprev4[q * 4 + j]; \
    d1 += sv.x*mv[j*4] + sv.y*mv[j*4+1] + sv.z*mv[j*4+2] + sv.w*mv[j*4+3]; \
    d2 += sv.x*wr0[j*4] + sv.y*wr0[j*4+1] + sv.z*wr0[j*4+2] + sv.w*wr0[j*4+3]; \
  } \
  d1 += __shfl_xor(d1, 1); d1 += __shfl_xor(d1, 2); \
  d2 += __shfl_xor(d2, 1); d2 += __shfl_xor(d2, 2); \
  Pa += d1; \
  float rec = gelu_tanh(Pa + d2 + br_r);      /* d2 has c0 folded in */ \
  if (q == 0) recurs[idx] = rec; \
  /* prefetch M for step T+2 into the just-consumed ring regs */ \
  { int _ns = (T) < 2048 ? (T) : 2047; \
    const uint4* _p = mt4 + (size_t)_ns * 512 + moff; \
    M0 = _p[0]; M1 = _p[1]; } \
  BARRIER_LG(); \
  float a2 = 0.0f; \
  _Pragma("unroll") \
  for (int j = 0; j < 4; ++j){ \
    float4 rv = recur4[q * 4 + j]; \
    a2 += rv.x*wsr[j*4] + rv.y*wsr[j*4+1] + rv.z*wsr[j*4+2] + rv.w*wsr[j*4+3]; \
  } \
  a2 += __shfl_xor(a2, 1); a2 += __shfl_xor(a2, 2); \
  float stt = gelu_tanh(a2 + XS + bs_s); \
  if (q == 0){ sprev[idx] = stt; sb[(size_t)((T) - 1) * 64 + idx] = stt; } \
  /* prefetch xstat for step T+2 directly into XS (last use was above) */ \
  { int _nx = (T) + 1 < 2048 ? (T) + 1 : 2047; \
    XS = xsp[(size_t)_nx * 64 + idx]; } \
  BARRIER_LG(); \
}

__global__ __launch_bounds__(256) void k_scan(
    const float* __restrict__ Wr, const float* __restrict__ br,
    const float* __restrict__ Ws, const float* __restrict__ bs,
    const float* __restrict__ phases, const float* __restrict__ xstat,
    const u16* __restrict__ MT, float* __restrict__ statsbuf){
  int b = blockIdx.x;
  int tid = threadIdx.x;
  int w = tid >> 6, l = tid & 63;
  int idx = w * 16 + (l >> 2);
  int q = l & 3;
  __shared__ __align__(16) float4 sprev4[16];
  __shared__ __align__(16) float4 recur4[16];
  float* sprev  = (float*)sprev4;
  float* recurs = (float*)recur4;
  float c0 = INV_L * cosf(TWO_PI * phases[0]);
  float wr0[16], wsr[16];
#pragma unroll
  for (int i = 0; i < 16; ++i) wr0[i] = c0 * Wr[(q * 16 + i) * 64 + idx];     // Wr rows f=0, c0 folded
#pragma unroll
  for (int i = 0; i < 16; ++i) wsr[i] = Ws[(128 + q * 16 + i) * 64 + idx];    // Ws rows 128..191
  float br_r = br[idx];
  float bs_s = bs[idx];
  float Pa = 0.0f;
  if (tid < 64) sprev[tid] = 0.0f;
  const uint4* mt4 = (const uint4*)MT;       // 512 uint4 per slot
  int moff = idx * 8 + q * 2;
  const float* xsp = xstat + (size_t)b * 2048 * 64;
  float* sb = statsbuf + (size_t)b * 2048 * 64;
  // 2-deep ring: step t uses M slot max(t-2,0) and xstat index t-1.
  // Prologue: A serves t=1 (slot 0, value irrelevant: sprev=0), B serves t=2 (slot 0).
  uint4 mA0, mA1, mB0, mB1;
  float xsA, xsB;
  { const uint4* _p = mt4 + moff; mA0 = _p[0]; mA1 = _p[1]; }
  { const uint4* _p = mt4 + moff; mB0 = _p[0]; mB1 = _p[1]; }
  xsA = xsp[idx];                  // t=1 -> index 0
  xsB = xsp[64 + idx];             // t=2 -> index 1
  __syncthreads();
  for (int t = 1; t <= 2048; t += 2){
    SSTEP(t,     mA0, mA1, xsA);
    SSTEP(t + 1, mB0, mB1, xsB);
  }
}

// --------------------------- K4: state materialization (bf16) ---------------
// state[b,t,f*64+s]: f>=1 cumsum of c_f(t)*stats; f=0 current term only.
__global__ __launch_bounds__(256) void k_state(const float* __restrict__ statsbuf,
    const float* __restrict__ ctab, u16* __restrict__ stateA){
  int g = blockIdx.x * 256 + threadIdx.x;       // [0, 32768)
  int s = g & 63, f = (g >> 6) & 15, b = g >> 10;
  const float* sp = statsbuf + (size_t)b * 2048 * 64 + s;
  u16* op = stateA + (size_t)b * 2048 * 1024 + f * 64 + s;
  float acc = 0.0f;
  const bool f0 = (f == 0);
  for (int t0 = 0; t0 < 2048; t0 += 8){
    float sv[8], cv[8];
#pragma unroll
    for (int i = 0; i < 8; ++i) sv[i] = sp[(size_t)(t0 + i) * 64];
#pragma unroll
    for (int i = 0; i < 8; ++i) cv[i] = ctab[(t0 + i + 1) * 16 + f];
#pragma unroll
    for (int i = 0; i < 8; ++i){
      acc = f0 ? (cv[i] * sv[i]) : fmaf(cv[i], sv[i], acc);
      op[(size_t)(t0 + i) * 1024] = f2bf(acc);
    }
  }
}

// --------------------------- K5: out = gelu(state @ Wo + bo) ----------------
// bf16 MFMA GEMM, 128x128 tile, 4 waves, 16x16x32, BT layout in LDS.
__global__ __launch_bounds__(256) void k_gemm(const u16* __restrict__ A,
    const u16* __restrict__ Bt, const float* __restrict__ bo, float* __restrict__ out){
  int nt = blockIdx.x & 7, mt = blockIdx.x >> 3;
  int m0 = mt * 128, n0 = nt * 128;
  __shared__ __align__(16) u16 As[128 * 32];
  __shared__ __align__(16) u16 Bs[128 * 32];
  int tid = threadIdx.x;
  int w = tid >> 6, l = tid & 63;
  int mh = (w & 1) * 64, nh = (w >> 1) * 64;
  int lr = l & 15, lq = l >> 4;
  f32x4 acc[4][4] = {};
  for (int k0 = 0; k0 < 1024; k0 += 32){
    int c = tid;
#pragma unroll
    for (int rr = 0; rr < 2; ++rr, c += 256){
      int row = c >> 2, qq = c & 3;
      *((uint4*)&As[row * 32 + qq * 8]) = *(const uint4*)(A  + (size_t)(m0 + row) * 1024 + k0 + qq * 8);
      *((uint4*)&Bs[row * 32 + qq * 8]) = *(const uint4*)(Bt + (size_t)(n0 + row) * 1024 + k0 + qq * 8);
    }
    __syncthreads();
    bf16x8 af[4], bfr[4];
#pragma unroll
    for (int i = 0; i < 4; ++i) af[i]  = *(const bf16x8*)&As[(mh + i * 16 + lr) * 32 + lq * 8];
#pragma unroll
    for (int i = 0; i < 4; ++i) bfr[i] = *(const bf16x8*)&Bs[(nh + i * 16 + lr) * 32 + lq * 8];
#pragma unroll
    for (int i = 0; i < 4; ++i)
#pragma unroll
      for (int j = 0; j < 4; ++j)
        acc[i][j] = __builtin_amdgcn_mfma_f32_16x16x32_bf16(af[i], bfr[j], acc[i][j], 0, 0, 0);
    __syncthreads();
  }
#pragma unroll
  for (int i = 0; i < 4; ++i){
#pragma unroll
    for (int j = 0; j < 4; ++j){
      int n = n0 + nh + j * 16 + lr;
      float bias = bo[n];
#pragma unroll
      for (int rg = 0; rg < 4; ++rg){
        int m = m0 + mh + i * 16 + lq * 4 + rg;
        out[(size_t)m * 1024 + n] = gelu_erf(acc[i][j][rg] + bias);
      }
    }
  }
}

// --------------------------- launcher ---------------------------------------
extern "C" void kernel_launch(void* const* d_in, const int* in_sizes, int n_in,
                              void* d_out, int out_size, void* d_ws, size_t ws_size,
                              hipStream_t stream){
  const float* x  = (const float*)d_in[0];
  const float* Wr = (const float*)d_in[1];
  const float* br = (const float*)d_in[2];
  const float* Ws = (const float*)d_in[3];
  const float* bs = (const float*)d_in[4];
  const float* Wo = (const float*)d_in[5];
  const float* bo = (const float*)d_in[6];
  const float* ph = (const float*)d_in[7];
  float* out = (float*)d_out;

  char* wp = (char*)d_ws;
  float* xstat    = (float*)(wp);                     // 16 MB: 65536 x 64 f32
  float* statsbuf = (float*)(wp + 16777216);          // 16 MB: 32 x 2048 x 64 f32
  u16*   MT       = (u16*)  (wp + 33554432);          // 16 MB: 2048 x 64 x 64 bf16
  float* ctab     = (float*)(wp + 50331648);          // 128 KB: 2049 x 16 f32
  u16*   WoT      = (u16*)  (wp + 50593792);          // 2 MB: 1024 x 1024 bf16
  u16*   stateA   = (u16*)  (wp + 52690944);          // 128 MB: 65536 x 1024 bf16

  hipLaunchKernelGGL(k_mprep, dim3(2048), dim3(256), 0, stream, Wr, ph, MT, ctab);
  hipLaunchKernelGGL(k_xstat, dim3(1024), dim3(256), 0, stream, x, Ws, xstat);
  hipLaunchKernelGGL(k_wot,   dim3(256),  dim3(256), 0, stream, Wo, WoT);
  hipLaunchKernelGGL(k_scan,  dim3(32),   dim3(256), 0, stream, Wr, br, Ws, bs, ph, xstat, MT, statsbuf);
  hipLaunchKernelGGL(k_state, dim3(128),  dim3(256), 0, stream, statsbuf, ctab, stateA);
  hipLaunchKernelGGL(k_gemm,  dim3(4096), dim3(256), 0, stream, stateA, WoT, bo, out);
}

// Round 5
// 1427.483 us; speedup vs baseline: 2.1381x; 1.4862x over previous
//
#include <hip/hip_runtime.h>
#include <math.h>

// ---------------------------------------------------------------------------
// FRU cell, decomposed:
//   state[f,s](t) = sum_{tau<=t} c_f(tau)*stats[s](tau)   (f>=1; f=0: current only)
//   c_f(t) = (1/L)*cos((2pi/L)*t*f + 2pi*phases[f])
// Scan only carries: Pa[r] = state_acc@Wr  (64 floats) and stats(t-1) (64 floats).
//   recur(t)  = gelu(Pa(t-1) + c0*stats(t-1)@Wr0 + br)
//   stats(t)  = gelu(xstat[b,t] + recur@Wsr + bs)
//   Pa(t)     = Pa(t-1) + stats(t)@M_t,  M_t precomputed (bf16, streamed)
// k_scan v5 = v4 (4-wave split, RAW lgkm-only barriers, 2-deep register ring
// prefetch) with critical-path surgery:
//   - quad reduce via DPP quad_perm (v_mov_dpp+v_add, ~4cy) instead of
//     __shfl_xor/ds_bpermute (~50cy DS latency, 6x per step, serial pairs).
//   - gelu: x*e*rcp(e+1) replaces (e-1)/(e+1) full f32 div sequence.
//   - dots as v_pk_fma_f32 (float2): 8-deep chains instead of 16-deep.
// Then: state materialized bf16 (cumsum over t), out = gelu(state@Wo + bo) as
// one big bf16 MFMA GEMM.
// ---------------------------------------------------------------------------

#define TWO_PI 6.283185307179586f
#define INV_L  (1.0f/2048.0f)

typedef unsigned short u16;
typedef __attribute__((ext_vector_type(8))) short bf16x8;   // 8 bf16 = 4 VGPRs
typedef __attribute__((ext_vector_type(4))) float f32x4;
typedef __attribute__((ext_vector_type(2))) float f32x2;

__device__ __forceinline__ float bf2f(u16 u){ return __uint_as_float(((unsigned int)u) << 16); }
__device__ __forceinline__ u16 f2bf(float x){
  unsigned int u = __float_as_uint(x);
  u += 0x7FFFu + ((u >> 16) & 1u);           // round-to-nearest-even
  return (u16)(u >> 16);
}
// unpack a dword holding 2 bf16 into a float2 (lo, hi)
__device__ __forceinline__ f32x2 bf2x2(unsigned int d){
  f32x2 v;
  v.x = __uint_as_float(d << 16);
  v.y = __uint_as_float(d & 0xffff0000u);
  return v;
}
__device__ __forceinline__ f32x2 fma2(f32x2 a, f32x2 b, f32x2 c){
#if defined(__has_builtin)
#if __has_builtin(__builtin_elementwise_fma)
  return __builtin_elementwise_fma(a, b, c);
#else
  return (f32x2){fmaf(a.x, b.x, c.x), fmaf(a.y, b.y, c.y)};
#endif
#else
  return (f32x2){fmaf(a.x, b.x, c.x), fmaf(a.y, b.y, c.y)};
#endif
}
// butterfly sum over the 4-lane quad via DPP quad_perm (VALU pipe, no DS ops)
__device__ __forceinline__ float qred(float x){
  x += __uint_as_float(__builtin_amdgcn_mov_dpp(__float_as_uint(x), 0xB1, 0xF, 0xF, true)); // xor1
  x += __uint_as_float(__builtin_amdgcn_mov_dpp(__float_as_uint(x), 0x4E, 0xF, 0xF, true)); // xor2
  return x;
}
// tanh-approx gelu, algebraically = 0.5x(1+tanh(y)) = x*e/(e+1), e=exp(2y).
// err <3e-4 abs (same approx as before; rcp adds ~1e-7). Attenuated ~50x
// through the (1/L) cumsum.
__device__ __forceinline__ float gelu_fast(float x){
  float x2 = x * x;
  float z = x * fmaf(0.07135481627f, x2, 1.5957691216f);   // z = 2y
  z = fminf(fmaxf(z, -24.0f), 24.0f);
  float e = __expf(z);
  return x * e * __builtin_amdgcn_rcpf(e + 1.0f);
}
__device__ __forceinline__ float gelu_erf(float x){
  return 0.5f * x * (1.0f + erff(x * 0.7071067811865475f));
}

// --------------------------- K2: M_t + ctab precompute ----------------------
// MT[slot=t-1][r][s] (bf16) = sum_{f=1..15} c_f(t) * Wr[(f*64+s)*64 + r]
// ctab[t][f] = c_f(t), t in [1,2048]
__global__ __launch_bounds__(256) void k_mprep(const float* __restrict__ Wr,
    const float* __restrict__ phases, u16* __restrict__ MT, float* __restrict__ ctab){
  int slot = blockIdx.x;                 // tau = slot+1
  float tau = (float)(slot + 1);
  __shared__ float cf[16];
  int tid = threadIdx.x;
  if (tid < 16){
    float c = INV_L * cosf((TWO_PI * INV_L) * tau * (float)tid + TWO_PI * phases[tid]);
    cf[tid] = c;
    ctab[(slot + 1) * 16 + tid] = c;
  }
  __syncthreads();
  int r = tid & 63, s0 = (tid >> 6) * 16;
  float acc[16];
#pragma unroll
  for (int i = 0; i < 16; ++i) acc[i] = 0.0f;
  for (int f = 1; f < 16; ++f){
    float c = cf[f];
    const float* wp = Wr + (f * 64 + s0) * 64 + r;   // coalesced over r (lanes)
#pragma unroll
    for (int i = 0; i < 16; ++i) acc[i] += c * wp[i * 64];
  }
  u16* o = MT + ((size_t)slot * 64 + r) * 64 + s0;
  uint4 p0, p1;
  p0.x = (unsigned)f2bf(acc[0])  | ((unsigned)f2bf(acc[1])  << 16);
  p0.y = (unsigned)f2bf(acc[2])  | ((unsigned)f2bf(acc[3])  << 16);
  p0.z = (unsigned)f2bf(acc[4])  | ((unsigned)f2bf(acc[5])  << 16);
  p0.w = (unsigned)f2bf(acc[6])  | ((unsigned)f2bf(acc[7])  << 16);
  p1.x = (unsigned)f2bf(acc[8])  | ((unsigned)f2bf(acc[9])  << 16);
  p1.y = (unsigned)f2bf(acc[10]) | ((unsigned)f2bf(acc[11]) << 16);
  p1.z = (unsigned)f2bf(acc[12]) | ((unsigned)f2bf(acc[13]) << 16);
  p1.w = (unsigned)f2bf(acc[14]) | ((unsigned)f2bf(acc[15]) << 16);
  ((uint4*)o)[0] = p0;
  ((uint4*)o)[1] = p1;
}

// --------------------------- K1: xstat = x @ Ws[0:128,:] --------------------
__global__ __launch_bounds__(256) void k_xstat(const float* __restrict__ x,
    const float* __restrict__ Ws, float* __restrict__ xstat){
  __shared__ float4 xt4[64 * 32];        // 64 rows x 128 cols
  __shared__ float partial[4][64];
  int tid = threadIdx.x;
  int row0 = blockIdx.x * 64;
  const float4* xg = (const float4*)(x + (size_t)row0 * 128);
  for (int i = tid; i < 2048; i += 256) xt4[i] = xg[i];
  int s = tid & 63, kq = tid >> 6;       // K split 4 x 32
  float wk[32];
#pragma unroll
  for (int j = 0; j < 32; ++j) wk[j] = Ws[(kq * 32 + j) * 64 + s];
  __syncthreads();
  for (int rr = 0; rr < 64; ++rr){
    const float4* xr = &xt4[rr * 32 + kq * 8];
    float a = 0.0f;
#pragma unroll
    for (int j = 0; j < 8; ++j){
      float4 v = xr[j];
      a += v.x * wk[j*4] + v.y * wk[j*4+1] + v.z * wk[j*4+2] + v.w * wk[j*4+3];
    }
    partial[kq][s] = a;
    __syncthreads();
    if (tid < 64)
      xstat[(size_t)(row0 + rr) * 64 + tid] =
        partial[0][tid] + partial[1][tid] + partial[2][tid] + partial[3][tid];
    __syncthreads();
  }
}

// --------------------------- K4b: WoT[n][k] = bf16(Wo[k][n]) ----------------
__global__ __launch_bounds__(256) void k_wot(const float* __restrict__ Wo, u16* __restrict__ WoT){
  __shared__ float tile[64][65];
  int bx = blockIdx.x & 15, by = blockIdx.x >> 4;
  int k0 = bx * 64, n0 = by * 64;
  int tid = threadIdx.x, ln = tid & 63, w = tid >> 6;
#pragma unroll
  for (int i = 0; i < 16; ++i){
    int kk = w * 16 + i;
    tile[kk][ln] = Wo[(size_t)(k0 + kk) * 1024 + n0 + ln];
  }
  __syncthreads();
#pragma unroll
  for (int i = 0; i < 16; ++i){
    int nn = w * 16 + i;
    WoT[(size_t)(n0 + nn) * 1024 + k0 + ln] = f2bf(tile[ln][nn]);
  }
}

// --------------------------- K3: the sequential scan ------------------------
// One workgroup per batch element. 256 threads: idx = w*16 + (l>>2) is the
// output index (r in stage A, s in stage B); q = l&3 splits K=64 into 4x16,
// reduced with DPP quad_perm butterflies (VALU, ~4cy) — no DS shuffle ops.
// RAW barrier: waits DS only; global prefetch stays outstanding across it.
#define BARRIER_LG() asm volatile("s_waitcnt lgkmcnt(0)\n\ts_barrier" ::: "memory")

// One scan step. Consumes ring regs (M0,M1,XS); reloads them (for step T+2)
// DIRECTLY (no copies) right after their last use.
#define SSTEP(T, M0, M1, XS) { \
  f32x2 m2[8]; \
  { unsigned mm0 = M0.x, mm1 = M0.y, mm2 = M0.z, mm3 = M0.w; \
    unsigned mm4 = M1.x, mm5 = M1.y, mm6 = M1.z, mm7 = M1.w; \
    m2[0] = bf2x2(mm0); m2[1] = bf2x2(mm1); m2[2] = bf2x2(mm2); m2[3] = bf2x2(mm3); \
    m2[4] = bf2x2(mm4); m2[5] = bf2x2(mm5); m2[6] = bf2x2(mm6); m2[7] = bf2x2(mm7); } \
  f32x2 accm = {0.f, 0.f}, accw = {0.f, 0.f}; \
  _Pragma("unroll") \
  for (int j = 0; j < 4; ++j){ \
    float4 sv = sprev4[q * 4 + j]; \
    f32x2 lo = {sv.x, sv.y}, hi = {sv.z, sv.w}; \
    accm = fma2(lo, m2[2*j],   accm); \
    accm = fma2(hi, m2[2*j+1], accm); \
    accw = fma2(lo, w02[2*j],   accw); \
    accw = fma2(hi, w02[2*j+1], accw); \
  } \
  float d1 = qred(accm.x + accm.y); \
  float d2 = qred(accw.x + accw.y); \
  Pa += d1; \
  float rec = gelu_fast(Pa + d2 + br_r);      /* d2 has c0 folded in */ \
  if (q == 0) recurs[idx] = rec; \
  /* prefetch M for step T+2 into the just-consumed ring regs */ \
  { int _ns = (T) < 2048 ? (T) : 2047; \
    const uint4* _p = mt4 + (size_t)_ns * 512 + moff; \
    M0 = _p[0]; M1 = _p[1]; } \
  BARRIER_LG(); \
  f32x2 accb = {0.f, 0.f}; \
  _Pragma("unroll") \
  for (int j = 0; j < 4; ++j){ \
    float4 rv = recur4[q * 4 + j]; \
    f32x2 lo = {rv.x, rv.y}, hi = {rv.z, rv.w}; \
    accb = fma2(lo, ws2[2*j],   accb); \
    accb = fma2(hi, ws2[2*j+1], accb); \
  } \
  float a2s = qred(accb.x + accb.y); \
  float stt = gelu_fast(a2s + XS + bs_s); \
  if (q == 0){ sprev[idx] = stt; sb[(size_t)((T) - 1) * 64 + idx] = stt; } \
  /* prefetch xstat for step T+2 directly into XS (last use was above) */ \
  { int _nx = (T) + 1 < 2048 ? (T) + 1 : 2047; \
    XS = xsp[(size_t)_nx * 64 + idx]; } \
  BARRIER_LG(); \
}

__global__ __launch_bounds__(256) void k_scan(
    const float* __restrict__ Wr, const float* __restrict__ br,
    const float* __restrict__ Ws, const float* __restrict__ bs,
    const float* __restrict__ phases, const float* __restrict__ xstat,
    const u16* __restrict__ MT, float* __restrict__ statsbuf){
  int b = blockIdx.x;
  int tid = threadIdx.x;
  int w = tid >> 6, l = tid & 63;
  int idx = w * 16 + (l >> 2);
  int q = l & 3;
  __shared__ __align__(16) float4 sprev4[16];
  __shared__ __align__(16) float4 recur4[16];
  float* sprev  = (float*)sprev4;
  float* recurs = (float*)recur4;
  float c0 = INV_L * cosf(TWO_PI * phases[0]);
  // resident weight columns as float2 pairs (c0 folded into Wr0 column)
  f32x2 w02[8], ws2[8];
#pragma unroll
  for (int i = 0; i < 8; ++i){
    w02[i].x = c0 * Wr[(q * 16 + 2 * i) * 64 + idx];
    w02[i].y = c0 * Wr[(q * 16 + 2 * i + 1) * 64 + idx];
    ws2[i].x = Ws[(128 + q * 16 + 2 * i) * 64 + idx];
    ws2[i].y = Ws[(128 + q * 16 + 2 * i + 1) * 64 + idx];
  }
  float br_r = br[idx];
  float bs_s = bs[idx];
  float Pa = 0.0f;
  if (tid < 64) sprev[tid] = 0.0f;
  const uint4* mt4 = (const uint4*)MT;       // 512 uint4 per slot
  int moff = idx * 8 + q * 2;
  const float* xsp = xstat + (size_t)b * 2048 * 64;
  float* sb = statsbuf + (size_t)b * 2048 * 64;
  // 2-deep ring: step t uses M slot max(t-2,0) and xstat index t-1.
  // Prologue: A serves t=1 (slot 0, value irrelevant: sprev=0), B serves t=2 (slot 0).
  uint4 mA0, mA1, mB0, mB1;
  float xsA, xsB;
  { const uint4* _p = mt4 + moff; mA0 = _p[0]; mA1 = _p[1]; }
  { const uint4* _p = mt4 + moff; mB0 = _p[0]; mB1 = _p[1]; }
  xsA = xsp[idx];                  // t=1 -> index 0
  xsB = xsp[64 + idx];             // t=2 -> index 1
  __syncthreads();
  for (int t = 1; t <= 2048; t += 2){
    SSTEP(t,     mA0, mA1, xsA);
    SSTEP(t + 1, mB0, mB1, xsB);
  }
}

// --------------------------- K4: state materialization (bf16) ---------------
// state[b,t,f*64+s]: f>=1 cumsum of c_f(t)*stats; f=0 current term only.
__global__ __launch_bounds__(256) void k_state(const float* __restrict__ statsbuf,
    const float* __restrict__ ctab, u16* __restrict__ stateA){
  int g = blockIdx.x * 256 + threadIdx.x;       // [0, 32768)
  int s = g & 63, f = (g >> 6) & 15, b = g >> 10;
  const float* sp = statsbuf + (size_t)b * 2048 * 64 + s;
  u16* op = stateA + (size_t)b * 2048 * 1024 + f * 64 + s;
  float acc = 0.0f;
  const bool f0 = (f == 0);
  for (int t0 = 0; t0 < 2048; t0 += 8){
    float sv[8], cv[8];
#pragma unroll
    for (int i = 0; i < 8; ++i) sv[i] = sp[(size_t)(t0 + i) * 64];
#pragma unroll
    for (int i = 0; i < 8; ++i) cv[i] = ctab[(t0 + i + 1) * 16 + f];
#pragma unroll
    for (int i = 0; i < 8; ++i){
      acc = f0 ? (cv[i] * sv[i]) : fmaf(cv[i], sv[i], acc);
      op[(size_t)(t0 + i) * 1024] = f2bf(acc);
    }
  }
}

// --------------------------- K5: out = gelu(state @ Wo + bo) ----------------
// bf16 MFMA GEMM, 128x128 tile, 4 waves, 16x16x32, BT layout in LDS.
__global__ __launch_bounds__(256) void k_gemm(const u16* __restrict__ A,
    const u16* __restrict__ Bt, const float* __restrict__ bo, float* __restrict__ out){
  int nt = blockIdx.x & 7, mt = blockIdx.x >> 3;
  int m0 = mt * 128, n0 = nt * 128;
  __shared__ __align__(16) u16 As[128 * 32];
  __shared__ __align__(16) u16 Bs[128 * 32];
  int tid = threadIdx.x;
  int w = tid >> 6, l = tid & 63;
  int mh = (w & 1) * 64, nh = (w >> 1) * 64;
  int lr = l & 15, lq = l >> 4;
  f32x4 acc[4][4] = {};
  for (int k0 = 0; k0 < 1024; k0 += 32){
    int c = tid;
#pragma unroll
    for (int rr = 0; rr < 2; ++rr, c += 256){
      int row = c >> 2, qq = c & 3;
      *((uint4*)&As[row * 32 + qq * 8]) = *(const uint4*)(A  + (size_t)(m0 + row) * 1024 + k0 + qq * 8);
      *((uint4*)&Bs[row * 32 + qq * 8]) = *(const uint4*)(Bt + (size_t)(n0 + row) * 1024 + k0 + qq * 8);
    }
    __syncthreads();
    bf16x8 af[4], bfr[4];
#pragma unroll
    for (int i = 0; i < 4; ++i) af[i]  = *(const bf16x8*)&As[(mh + i * 16 + lr) * 32 + lq * 8];
#pragma unroll
    for (int i = 0; i < 4; ++i) bfr[i] = *(const bf16x8*)&Bs[(nh + i * 16 + lr) * 32 + lq * 8];
#pragma unroll
    for (int i = 0; i < 4; ++i)
#pragma unroll
      for (int j = 0; j < 4; ++j)
        acc[i][j] = __builtin_amdgcn_mfma_f32_16x16x32_bf16(af[i], bfr[j], acc[i][j], 0, 0, 0);
    __syncthreads();
  }
#pragma unroll
  for (int i = 0; i < 4; ++i){
#pragma unroll
    for (int j = 0; j < 4; ++j){
      int n = n0 + nh + j * 16 + lr;
      float bias = bo[n];
#pragma unroll
      for (int rg = 0; rg < 4; ++rg){
        int m = m0 + mh + i * 16 + lq * 4 + rg;
        out[(size_t)m * 1024 + n] = gelu_erf(acc[i][j][rg] + bias);
      }
    }
  }
}

// --------------------------- launcher ---------------------------------------
extern "C" void kernel_launch(void* const* d_in, const int* in_sizes, int n_in,
                              void* d_out, int out_size, void* d_ws, size_t ws_size,
                              hipStream_t stream){
  const float* x  = (const float*)d_in[0];
  const float* Wr = (const float*)d_in[1];
  const float* br = (const float*)d_in[2];
  const float* Ws = (const float*)d_in[3];
  const float* bs = (const float*)d_in[4];
  const float* Wo = (const float*)d_in[5];
  const float* bo = (const float*)d_in[6];
  const float* ph = (const float*)d_in[7];
  float* out = (float*)d_out;

  char* wp = (char*)d_ws;
  float* xstat    = (float*)(wp);                     // 16 MB: 65536 x 64 f32
  float* statsbuf = (float*)(wp + 16777216);          // 16 MB: 32 x 2048 x 64 f32
  u16*   MT       = (u16*)  (wp + 33554432);          // 16 MB: 2048 x 64 x 64 bf16
  float* ctab     = (float*)(wp + 50331648);          // 128 KB: 2049 x 16 f32
  u16*   WoT      = (u16*)  (wp + 50593792);          // 2 MB: 1024 x 1024 bf16
  u16*   stateA   = (u16*)  (wp + 52690944);          // 128 MB: 65536 x 1024 bf16

  hipLaunchKernelGGL(k_mprep, dim3(2048), dim3(256), 0, stream, Wr, ph, MT, ctab);
  hipLaunchKernelGGL(k_xstat, dim3(1024), dim3(256), 0, stream, x, Ws, xstat);
  hipLaunchKernelGGL(k_wot,   dim3(256),  dim3(256), 0, stream, Wo, WoT);
  hipLaunchKernelGGL(k_scan,  dim3(32),   dim3(256), 0, stream, Wr, br, Ws, bs, ph, xstat, MT, statsbuf);
  hipLaunchKernelGGL(k_state, dim3(128),  dim3(256), 0, stream, statsbuf, ctab, stateA);
  hipLaunchKernelGGL(k_gemm,  dim3(4096), dim3(256), 0, stream, stateA, WoT, bo, out);
}